// Round 15
// baseline (443.404 us; speedup 1.0000x reference)
//
#include <hip/hip_runtime.h>

// HGNN layer, B=4, N=E=4096, D=128, fp32 in/out.
// Round 15: R13 baseline (404us, KS=2) + (a) MFMA mlp (x@W and x@theta from
// one LDS staging), (b) btrans+lists fused into one kernel (lane-owns-edge,
// prefetched tn loop). GEMM/gathers/bmask frozen at R13.

typedef __bf16 bf16;
typedef bf16 bf16x8 __attribute__((ext_vector_type(8)));
typedef float f32x4 __attribute__((ext_vector_type(4)));
typedef unsigned long long u64;
typedef unsigned short u16;
typedef u16 u16x8 __attribute__((ext_vector_type(8)));

#define LDK 72   // LDS row stride for 64-k tiles (gemm)
#define LDM 136  // LDS row stride for 128-k tiles (mlp)
#define SWZ(r, c) ((c) ^ ((((r) >> 3) & 7) << 3))
#define CAP 192

union BPack { bf16 h[2]; unsigned int u; };
static __device__ __forceinline__ bf16 tob(float f) { return (bf16)f; }

// ---------------------------------------------------------------------------
// K1 (MFMA): xw = x @ W + b, xt = x @ theta. 64 rows/block, 256 thr = 4 waves.
__global__ __launch_bounds__(256) void mlp_k(const float* __restrict__ x,
                                             const float* __restrict__ W,
                                             const float* __restrict__ bias,
                                             const float* __restrict__ theta,
                                             float* __restrict__ xw,
                                             float* __restrict__ xt) {
    __shared__ __align__(16) bf16 Xs[64][LDM];
    __shared__ __align__(16) bf16 Ws[128][LDM];  // Ws[d][k] = W[k][d]
    const int t = threadIdx.x;
    const long r0 = (long)blockIdx.x * 64;

    // stage x tile: thread t -> row t>>2, 32 floats at (t&3)*32
    {
        const int row = t >> 2, c = (t & 3) * 32;
        const float* g = x + (r0 + row) * 128 + c;
#pragma unroll
        for (int j8 = 0; j8 < 4; ++j8) {
            float4 v0 = *(const float4*)(g + j8 * 8);
            float4 v1 = *(const float4*)(g + j8 * 8 + 4);
            bf16x8 p;
            p[0] = tob(v0.x); p[1] = tob(v0.y); p[2] = tob(v0.z); p[3] = tob(v0.w);
            p[4] = tob(v1.x); p[5] = tob(v1.y); p[6] = tob(v1.z); p[7] = tob(v1.w);
            *(bf16x8*)&Xs[row][c + j8 * 8] = p;
        }
    }
    // stage W transposed: thread t reads W[k=t>>1][(t&1)*64 .. +64]
    {
        const int wk = t >> 1, wh = (t & 1) * 64;
        const float* g = W + wk * 128 + wh;
#pragma unroll
        for (int j = 0; j < 64; j += 4) {
            float4 v = *(const float4*)(g + j);
            Ws[wh + j + 0][wk] = tob(v.x);
            Ws[wh + j + 1][wk] = tob(v.y);
            Ws[wh + j + 2][wk] = tob(v.z);
            Ws[wh + j + 3][wk] = tob(v.w);
        }
    }
    __syncthreads();

    const int wave = t >> 6, lane = t & 63;
    const int lr = lane & 15, kb = lane >> 4;
    const int wm = wave * 16;

    f32x4 acc[8];
#pragma unroll
    for (int ct = 0; ct < 8; ++ct) acc[ct] = (f32x4){0.f, 0.f, 0.f, 0.f};

#pragma unroll
    for (int step = 0; step < 4; ++step) {
        const int ka = step * 32 + kb * 8;
        bf16x8 af = *(const bf16x8*)&Xs[wm + lr][ka];
#pragma unroll
        for (int ct = 0; ct < 8; ++ct) {
            bf16x8 bfr = *(const bf16x8*)&Ws[ct * 16 + lr][ka];
            acc[ct] = __builtin_amdgcn_mfma_f32_16x16x32_bf16(af, bfr, acc[ct], 0, 0, 0);
        }
    }

    // xt: row = t>>2, quarter q = t&3 (lanes 4r..4r+3 contiguous in wave)
    {
        const int row = t >> 2, q = t & 3;
        float p = 0.f;
#pragma unroll
        for (int kk = 0; kk < 32; ++kk)
            p += (float)Xs[row][q * 32 + kk] * theta[q * 32 + kk];
        p += __shfl_down(p, 2);
        p += __shfl_down(p, 1);
        if (q == 0) xt[r0 + row] = p;
    }

    // epilogue: col = ct*16+lr, local row = kb*4+i
#pragma unroll
    for (int ct = 0; ct < 8; ++ct) {
        const int col = ct * 16 + lr;
        const float bd = bias[col];
#pragma unroll
        for (int i = 0; i < 4; ++i)
            xw[(r0 + wm + kb * 4 + i) * 128 + col] = acc[ct][i] + bd;
    }
}

// ---------------------------------------------------------------------------
// Row bitmask + fused ELL row-list build (R13 proven).
__global__ __launch_bounds__(256) void bmask_lists_k(const float* __restrict__ inc,
                                                     u64* __restrict__ rowmask,
                                                     u16* __restrict__ idx,
                                                     int* __restrict__ cnts) {
    const int b = blockIdx.y;
    const int n = blockIdx.x * 4 + (threadIdx.x >> 6);
    const int l = threadIdx.x & 63;
    const float* p = inc + ((long)b << 24) + (long)n * 4096 + l * 64;
    u64 w = 0;
#pragma unroll
    for (int j = 0; j < 16; ++j) {
        const float4 v = *(const float4*)(p + j * 4);
        w |= (u64)(v.x != 0.f ? 1u : 0u) << (4 * j);
        w |= (u64)(v.y != 0.f ? 1u : 0u) << (4 * j + 1);
        w |= (u64)(v.z != 0.f ? 1u : 0u) << (4 * j + 2);
        w |= (u64)(v.w != 0.f ? 1u : 0u) << (4 * j + 3);
    }
    const long rowid = (long)b * 4096 + n;
    rowmask[rowid * 64 + l] = w;

    const int pc = __popcll(w);
    int pre = pc;
#pragma unroll
    for (int o = 1; o < 64; o <<= 1) {
        int t = __shfl_up(pre, o);
        if (l >= o) pre += t;
    }
    if (l == 63) cnts[rowid] = pre;
    u16* op = idx + rowid * CAP;
    int k = pre - pc;
    u64 m = w;
    while (m) {
        const int bit = __builtin_ctzll(m);
        m &= m - 1;
        if (k < CAP) op[k] = (u16)(l * 64 + bit);
        ++k;
    }
}

// ---------------------------------------------------------------------------
// Fused 64x64 bit transpose + ELL col-list build. One wave per 64-e tile;
// lane l owns e = te*64+l end-to-end; next-tn load prefetched.
__global__ __launch_bounds__(64) void btrans_lists_k(const u64* __restrict__ rowmask,
                                                     u64* __restrict__ colmask,
                                                     u16* __restrict__ idx,
                                                     int* __restrict__ cnts) {
    const int te = blockIdx.x, b = blockIdx.y;
    const int l = threadIdx.x;
    __shared__ u64 w[64];
    const long rowid = (long)b * 4096 + te * 64 + l;
    u16* op = idx + rowid * CAP;
    int k = 0;

    u64 nx = rowmask[((long)b * 4096 + l) * 64 + te];  // tn=0, row j=l
    for (int tn = 0; tn < 64; ++tn) {
        w[l] = nx;
        __syncthreads();
        if (tn < 63) nx = rowmask[((long)b * 4096 + (tn + 1) * 64 + l) * 64 + te];
        u64 o = 0;
#pragma unroll 8
        for (int j = 0; j < 64; ++j) o |= ((w[j] >> l) & 1ull) << j;
        colmask[rowid * 64 + tn] = o;
        while (o) {
            const int bit = __builtin_ctzll(o);
            o &= o - 1;
            if (k < CAP) op[k] = (u16)(tn * 64 + bit);
            ++k;
        }
        __syncthreads();
    }
    cnts[rowid] = k;
}

// ---------------------------------------------------------------------------
// masked softmax over E per batch.
__global__ void softmax_k(const float* __restrict__ sc, const int* __restrict__ mask,
                          float* __restrict__ attn) {
    const int b = blockIdx.x, t = threadIdx.x;
    __shared__ float red[1024];
    const float* sb = sc + b * 4096;
    const int* mb = mask + b * 4096;

    float mx = -1e30f;
    for (int e = t; e < 4096; e += 1024)
        if (mb[e] != 0) mx = fmaxf(mx, sb[e]);
    red[t] = mx;
    __syncthreads();
    for (int st = 512; st > 0; st >>= 1) {
        if (t < st) red[t] = fmaxf(red[t], red[t + st]);
        __syncthreads();
    }
    mx = red[0];
    __syncthreads();

    float sum = 0.f;
    for (int e = t; e < 4096; e += 1024)
        if (mb[e] != 0) sum += expf(sb[e] - mx);
    red[t] = sum;
    __syncthreads();
    for (int st = 512; st > 0; st >>= 1) {
        if (t < st) red[t] += red[t + st];
        __syncthreads();
    }
    const float inv = 1.f / red[0];
    for (int e = t; e < 4096; e += 1024)
        attn[b * 4096 + e] = (mb[e] != 0) ? expf(sb[e] - mx) * inv : 0.f;
}

// ---------------------------------------------------------------------------
// hxw_s = attn (per edge row) * hxw.
__global__ __launch_bounds__(256) void scale_k(const float* __restrict__ hxw,
                                               const float* __restrict__ att,
                                               float* __restrict__ outp) {
    const long i4 = (long)blockIdx.x * 256 + threadIdx.x;
    float4 v = ((const float4*)hxw)[i4];
    const float s = att[i4 >> 5];
    v.x *= s; v.y *= s; v.z *= s; v.w *= s;
    ((float4*)outp)[i4] = v;
}

// ---------------------------------------------------------------------------
// Sum of split-K partials, optional +eps*H:  O = sum_s P_s [+ eps*H].
template <int KSP, bool EPS>
__global__ __launch_bounds__(256) void pairsum_k(const float* __restrict__ P,
                                                 const float* __restrict__ H,
                                                 const float* __restrict__ epsp,
                                                 float* __restrict__ O) {
    const long i4 = (long)blockIdx.x * 256 + threadIdx.x;
    float4 a = ((const float4*)P)[i4];
#pragma unroll
    for (int s = 1; s < KSP; ++s) {
        float4 c = ((const float4*)P)[i4 + (long)s * 524288];
        a.x += c.x; a.y += c.y; a.z += c.z; a.w += c.w;
    }
    if (EPS) {
        const float e = epsp[0];
        float4 h = ((const float4*)H)[i4];
        a.x += e * h.x; a.y += e * h.y; a.z += e * h.z; a.w += e * h.w;
    }
    ((float4*)O)[i4] = a;
}

// ---------------------------------------------------------------------------
// Plain ELL gather, 8-edge rounds with index double-buffer prefetch (R13).
template <bool HXT, bool EPI>
__global__ __launch_bounds__(256) void gatherE_k(
    const u16* __restrict__ idx, const int* __restrict__ cnts,
    const u64* __restrict__ mask, const float* __restrict__ src,
    const float* __restrict__ xt,
    const float* __restrict__ bng, const float* __restrict__ bnb,
    const float* __restrict__ bnm, const float* __restrict__ bnv,
    float* __restrict__ out, float* __restrict__ hxt) {
    const int bid = blockIdx.x;
    const int slot = bid & 7;
    const int b = slot >> 1;
    const int chunk = (bid >> 3) * 2 + (slot & 1);
    const int r = chunk * 4 + (threadIdx.x >> 6);
    const int l = threadIdx.x & 63;
    const long rowid = (long)b * 4096 + r;
    const int cnt = cnts[rowid];
    const u16* ip = idx + rowid * CAP;
    const float* S = src + (long)b * 524288;
    const float* xb = xt + (long)b * 4096;
    const int c0 = 2 * l;

    float ax0 = 0.f, ax1 = 0.f, ax2 = 0.f, ax3 = 0.f;
    float ax4 = 0.f, ax5 = 0.f, ax6 = 0.f, ax7 = 0.f;
    float ay0 = 0.f, ay1 = 0.f, ay2 = 0.f, ay3 = 0.f;
    float ay4 = 0.f, ay5 = 0.f, ay6 = 0.f, ay7 = 0.f;
    float hacc = 0.f;

    const int n = cnt < CAP ? cnt : CAP;
    int i = 0;
    if (n >= 8) {
        u16x8 ia = *(const u16x8*)ip;
        for (; i + 8 <= n; i += 8) {
            const int e0 = ia[0], e1 = ia[1], e2 = ia[2], e3 = ia[3];
            const int e4 = ia[4], e5 = ia[5], e6 = ia[6], e7 = ia[7];
            const float2 v0 = *(const float2*)(S + (long)e0 * 128 + c0);
            const float2 v1 = *(const float2*)(S + (long)e1 * 128 + c0);
            const float2 v2 = *(const float2*)(S + (long)e2 * 128 + c0);
            const float2 v3 = *(const float2*)(S + (long)e3 * 128 + c0);
            const float2 v4 = *(const float2*)(S + (long)e4 * 128 + c0);
            const float2 v5 = *(const float2*)(S + (long)e5 * 128 + c0);
            const float2 v6 = *(const float2*)(S + (long)e6 * 128 + c0);
            const float2 v7 = *(const float2*)(S + (long)e7 * 128 + c0);
            const bool more = (i + 16 <= n);
            u16x8 ib;
            if (more) ib = *(const u16x8*)(ip + i + 8);
            if (HXT)
                hacc += ((xb[e0] + xb[e1]) + (xb[e2] + xb[e3])) +
                        ((xb[e4] + xb[e5]) + (xb[e6] + xb[e7]));
            ax0 += v0.x; ay0 += v0.y; ax1 += v1.x; ay1 += v1.y;
            ax2 += v2.x; ay2 += v2.y; ax3 += v3.x; ay3 += v3.y;
            ax4 += v4.x; ay4 += v4.y; ax5 += v5.x; ay5 += v5.y;
            ax6 += v6.x; ay6 += v6.y; ax7 += v7.x; ay7 += v7.y;
            if (more) ia = ib;
        }
    }
    for (; i < n; ++i) {
        const int e = ip[i];
        const float2 v = *(const float2*)(S + (long)e * 128 + c0);
        if (HXT) hacc += xb[e];
        ax0 += v.x; ay0 += v.y;
    }

    if (cnt > CAP) {  // astronomically rare; exact fallback
        const u64 wrd = mask[rowid * 64 + l];
        int seen = 0;
        for (int wi = 0; wi < 64; ++wi) {
            u64 m = __shfl(wrd, wi);
            const int pc = __popcll(m);
            if (seen + pc > CAP) {
                int tk = CAP - seen;
                if (tk < 0) tk = 0;
                for (int t = 0; t < tk; ++t) m &= m - 1;
                while (m) {
                    const int bit = __builtin_ctzll(m);
                    m &= m - 1;
                    const int e = (wi << 6) + bit;
                    const float2 v = *(const float2*)(S + (long)e * 128 + c0);
                    if (HXT) hacc += xb[e];
                    ax0 += v.x; ay0 += v.y;
                }
            }
            seen += pc;
        }
    }

    float ax = ((ax0 + ax1) + (ax2 + ax3)) + ((ax4 + ax5) + (ax6 + ax7));
    float ay = ((ay0 + ay1) + (ay2 + ay3)) + ((ay4 + ay5) + (ay6 + ay7));
    if (EPI) {
        float t0 = (ax >= 0.f) ? ax : 0.01f * ax;
        float t1 = (ay >= 0.f) ? ay : 0.01f * ay;
        ax = (t0 - bnm[c0]) * rsqrtf(bnv[c0] + 1e-5f) * bng[c0] + bnb[c0];
        ay = (t1 - bnm[c0 + 1]) * rsqrtf(bnv[c0 + 1] + 1e-5f) * bng[c0 + 1] + bnb[c0 + 1];
    }
    *(float2*)&out[(long)b * 524288 + (long)r * 128 + c0] = (float2){ax, ay};
    if (HXT && l == 0) hxt[rowid] = hacc;
}

// ---------------------------------------------------------------------------
// Dense bf16-MFMA GEMM (R12/R13, frozen): 128x128 tile, 1024 thr = 16 waves,
// BK=64, LDS dbuf, 2 named reg sets, 1 barrier/phase, XCD-affinity 1D grid.
template <int KS>
__global__ __launch_bounds__(1024, 4) void gemm_dense(
    const float* __restrict__ A, const float* __restrict__ Bsrc,
    float* __restrict__ P) {
    __shared__ __align__(16) bf16 As[2][128][LDK];
    __shared__ __align__(16) bf16 Bs[2][128][LDK];

    const int tid = threadIdx.x;
    const int bid = blockIdx.x;
    const int slot = bid & 7;
    const int b = slot >> 1;
    const int sub = (bid >> 3) * 2 + (slot & 1);
    const int ksi = sub % KS;
    const int m0 = (sub / KS) * 128;
    constexpr int KCH = 4096 / KS;
    const int kbeg = ksi * KCH, kend = kbeg + KCH;
    const long Aoff = (long)b << 24;
    const long Boff = (long)b * 524288;

    const int wave = tid >> 6, lane = tid & 63;
    const int lr = lane & 15, kb = lane >> 4;
    const int wm = (wave >> 2) * 32, wn = (wave & 3) * 32;

    const int ar = tid >> 3, ak = (tid & 7) * 8;
    const int bd4 = (tid & 31) * 4, bk2 = (tid >> 5) * 2;

    const float* Abase = A + Aoff + (long)(m0 + ar) * 4096 + ak;
    const float* Bbase = Bsrc + Boff + (long)bk2 * 128 + bd4;

    f32x4 acc[2][2];
#pragma unroll
    for (int mf = 0; mf < 2; ++mf)
#pragma unroll
        for (int nf = 0; nf < 2; ++nf) acc[mf][nf] = (f32x4){0.f, 0.f, 0.f, 0.f};

    float4 pa0A, pa1A, pb0A, pb1A;
    float4 pa0B, pa1B, pb0B, pb1B;

#define GLOAD(S, kk)                                                        \
    {                                                                       \
        const float* ga = Abase + (kk);                                     \
        pa0##S = *(const float4*)ga;                                        \
        pa1##S = *(const float4*)(ga + 4);                                  \
        const float* gb = Bbase + (long)(kk) * 128;                         \
        pb0##S = *(const float4*)gb;                                        \
        pb1##S = *(const float4*)(gb + 128);                                \
    }

#define STAGE(S, bu)                                                        \
    {                                                                       \
        bf16x8 p;                                                           \
        p[0] = tob(pa0##S.x); p[1] = tob(pa0##S.y); p[2] = tob(pa0##S.z); p[3] = tob(pa0##S.w); \
        p[4] = tob(pa1##S.x); p[5] = tob(pa1##S.y); p[6] = tob(pa1##S.z); p[7] = tob(pa1##S.w); \
        *(bf16x8*)&As[bu][ar][SWZ(ar, ak)] = p;                             \
        float va[4] = {pb0##S.x, pb0##S.y, pb0##S.z, pb0##S.w};             \
        float vb[4] = {pb1##S.x, pb1##S.y, pb1##S.z, pb1##S.w};             \
        _Pragma("unroll")                                                   \
        for (int j = 0; j < 4; ++j) {                                       \
            BPack q; q.h[0] = tob(va[j]); q.h[1] = tob(vb[j]);              \
            *(unsigned int*)&Bs[bu][bd4 + j][SWZ(bd4 + j, bk2)] = q.u;      \
        }                                                                   \
    }

#define MFMA_STEP(bu)                                                       \
    {                                                                       \
        _Pragma("unroll")                                                   \
        for (int ks = 0; ks < 2; ++ks) {                                    \
            const int ka = ks * 32 + kb * 8;                                \
            bf16x8 af[2], bfr[2];                                           \
            _Pragma("unroll")                                               \
            for (int mf = 0; mf < 2; ++mf) {                                \
                const int rA = wm + mf * 16 + lr;                           \
                af[mf] = *(const bf16x8*)&As[bu][rA][SWZ(rA, ka)];          \
            }                                                               \
            _Pragma("unroll")                                               \
            for (int nf = 0; nf < 2; ++nf) {                                \
                const int rB = wn + nf * 16 + lr;                           \
                bfr[nf] = *(const bf16x8*)&Bs[bu][rB][SWZ(rB, ka)];         \
            }                                                               \
            _Pragma("unroll")                                               \
            for (int mf = 0; mf < 2; ++mf)                                  \
                _Pragma("unroll")                                           \
                for (int nf = 0; nf < 2; ++nf)                              \
                    acc[mf][nf] = __builtin_amdgcn_mfma_f32_16x16x32_bf16(  \
                        af[mf], bfr[nf], acc[mf][nf], 0, 0, 0);             \
        }                                                                   \
    }

    GLOAD(A, kbeg);
    GLOAD(B, kbeg + 64);
    STAGE(A, 0);
    __syncthreads();

    for (int kk = kbeg; kk < kend; kk += 128) {
        MFMA_STEP(0);
        STAGE(B, 1);
        if (kk + 128 < kend) GLOAD(A, kk + 128);
        __syncthreads();
        MFMA_STEP(1);
        if (kk + 128 < kend) {
            STAGE(A, 0);
            if (kk + 192 < kend) GLOAD(B, kk + 192);
            __syncthreads();
        }
    }
#undef GLOAD
#undef STAGE
#undef MFMA_STEP

    float* Cp = P + (long)(ksi * 4 + b) * 524288;
#pragma unroll
    for (int mf = 0; mf < 2; ++mf) {
        const int rb = m0 + wm + mf * 16 + kb * 4;
#pragma unroll
        for (int nf = 0; nf < 2; ++nf) {
            const int col = wn + nf * 16 + lr;
#pragma unroll
            for (int i = 0; i < 4; ++i)
                Cp[(long)(rb + i) * 128 + col] = acc[mf][nf][i];
        }
    }
}

// ---------------------------------------------------------------------------
template <int KS>
static void run_all(const float* incident, const float* degree_v, const float* degree_e,
                    const float* x, const int* e_masks, const float* mlp_W,
                    const float* mlp_b, const float* theta, const float* epsp,
                    const float* bng, const float* bnb, const float* bnm,
                    const float* bnv, float* out, float* ws, hipStream_t stream) {
    float* xw    = ws;                        // 2M floats
    float* hxw   = ws + 2097152;              // 2M
    float* hxw_s = ws + 4194304;              // 2M
    float* t1    = ws + 6291456;              // 2M
    float* Pd    = ws + 8388608;              // KS*2M
    float* Psum  = Pd + (long)KS * 2097152;   // 2M
    float* tail  = Psum + 2097152;
    u64* rowmask = (u64*)tail;                       // 1M u64
    u64* colmask = rowmask + 1048576;                // 1M u64
    u16* rowidx = (u16*)(colmask + 1048576);         // 16384*CAP u16
    u16* colidx = rowidx + 16384 * CAP;
    int* rowcnt = (int*)(colidx + 16384 * CAP);      // 16K int
    int* colcnt = rowcnt + 16384;
    float* xt  = (float*)(colcnt + 16384);
    float* hxt = xt + 16384;
    float* att = hxt + 16384;

    mlp_k<<<256, 256, 0, stream>>>(x, mlp_W, mlp_b, theta, xw, xt);
    bmask_lists_k<<<dim3(1024, 4), 256, 0, stream>>>(incident, rowmask, rowidx, rowcnt);
    btrans_lists_k<<<dim3(64, 4), 64, 0, stream>>>(rowmask, colmask, colidx, colcnt);

    // G1: hxw = Ht @ xw  (+ hxt = Ht @ xt)
    gatherE_k<true, false><<<4096, 256, 0, stream>>>(
        colidx, colcnt, colmask, xw, xt, nullptr, nullptr, nullptr, nullptr,
        hxw, hxt);
    softmax_k<<<4, 1024, 0, stream>>>(hxt, e_masks, att);
    scale_k<<<2048, 256, 0, stream>>>(hxw, att, hxw_s);
    // G2: t1 = incident @ hxw_s
    gatherE_k<false, false><<<4096, 256, 0, stream>>>(
        rowidx, rowcnt, rowmask, hxw_s, xt, nullptr, nullptr, nullptr, nullptr,
        t1, nullptr);
    // G3: Pd = degree_v @ t1
    gemm_dense<KS><<<32 * KS * 4, 1024, 0, stream>>>(degree_v, t1, Pd);
    pairsum_k<KS, false><<<2048, 256, 0, stream>>>(Pd, nullptr, nullptr, Psum);
    // G4: t1 = Ht @ Psum
    gatherE_k<false, false><<<4096, 256, 0, stream>>>(
        colidx, colcnt, colmask, Psum, xt, nullptr, nullptr, nullptr, nullptr,
        t1, nullptr);
    // G5: Pd = degree_e @ t1
    gemm_dense<KS><<<32 * KS * 4, 1024, 0, stream>>>(degree_e, t1, Pd);
    pairsum_k<KS, true><<<2048, 256, 0, stream>>>(Pd, hxw, epsp, Psum);
    // G6: out = BN(leaky(incident @ Psum))
    gatherE_k<false, true><<<4096, 256, 0, stream>>>(
        rowidx, rowcnt, rowmask, Psum, xt, bng, bnb, bnm, bnv, out, nullptr);
}

extern "C" void kernel_launch(void* const* d_in, const int* in_sizes, int n_in,
                              void* d_out, int out_size, void* d_ws, size_t ws_size,
                              hipStream_t stream) {
    const float* incident = (const float*)d_in[0];
    const float* degree_v = (const float*)d_in[1];
    const float* degree_e = (const float*)d_in[2];
    const float* x        = (const float*)d_in[3];
    const int*   e_masks  = (const int*)d_in[4];
    const float* mlp_W    = (const float*)d_in[5];
    const float* mlp_b    = (const float*)d_in[6];
    const float* theta    = (const float*)d_in[7];
    const float* epsp     = (const float*)d_in[8];
    const float* bng      = (const float*)d_in[9];
    const float* bnb      = (const float*)d_in[10];
    const float* bnm      = (const float*)d_in[11];
    const float* bnv      = (const float*)d_in[12];
    float* out = (float*)d_out;
    float* ws = (float*)d_ws;

    if (ws_size >= 110000000ull)
        run_all<2>(incident, degree_v, degree_e, x, e_masks, mlp_W, mlp_b, theta,
                   epsp, bng, bnb, bnm, bnv, out, ws, stream);
    else
        run_all<1>(incident, degree_v, degree_e, x, e_masks, mlp_W, mlp_b, theta,
                   epsp, bng, bnb, bnm, bnv, out, ws, stream);
}

// Round 16
// 385.426 us; speedup vs baseline: 1.1504x; 1.1504x over previous
//
#include <hip/hip_runtime.h>

// HGNN layer, B=4, N=E=4096, D=128, fp32 in/out.
// Round 16: R13 baseline (404us) + MFMA mlp ONLY (R15's btrans/lists fusion
// reverted — it was 1 wave/CU serial, the regression). Clean A/B for mlp.

typedef __bf16 bf16;
typedef bf16 bf16x8 __attribute__((ext_vector_type(8)));
typedef float f32x4 __attribute__((ext_vector_type(4)));
typedef unsigned long long u64;
typedef unsigned short u16;
typedef u16 u16x8 __attribute__((ext_vector_type(8)));

#define LDK 72   // LDS row stride for 64-k tiles (gemm)
#define LDM 136  // LDS row stride for 128-k tiles (mlp)
#define SWZ(r, c) ((c) ^ ((((r) >> 3) & 7) << 3))
#define CAP 192

union BPack { bf16 h[2]; unsigned int u; };
static __device__ __forceinline__ bf16 tob(float f) { return (bf16)f; }

// ---------------------------------------------------------------------------
// K1 (MFMA): xw = x @ W + b, xt = x @ theta. 64 rows/block, 256 thr = 4 waves.
__global__ __launch_bounds__(256) void mlp_k(const float* __restrict__ x,
                                             const float* __restrict__ W,
                                             const float* __restrict__ bias,
                                             const float* __restrict__ theta,
                                             float* __restrict__ xw,
                                             float* __restrict__ xt) {
    __shared__ __align__(16) bf16 Xs[64][LDM];
    __shared__ __align__(16) bf16 Ws[128][LDM];  // Ws[d][k] = W[k][d]
    const int t = threadIdx.x;
    const long r0 = (long)blockIdx.x * 64;

    // stage x tile: thread t -> row t>>2, 32 floats at (t&3)*32
    {
        const int row = t >> 2, c = (t & 3) * 32;
        const float* g = x + (r0 + row) * 128 + c;
#pragma unroll
        for (int j8 = 0; j8 < 4; ++j8) {
            float4 v0 = *(const float4*)(g + j8 * 8);
            float4 v1 = *(const float4*)(g + j8 * 8 + 4);
            bf16x8 p;
            p[0] = tob(v0.x); p[1] = tob(v0.y); p[2] = tob(v0.z); p[3] = tob(v0.w);
            p[4] = tob(v1.x); p[5] = tob(v1.y); p[6] = tob(v1.z); p[7] = tob(v1.w);
            *(bf16x8*)&Xs[row][c + j8 * 8] = p;
        }
    }
    // stage W transposed: thread t reads W[k=t>>1][(t&1)*64 .. +64]
    {
        const int wk = t >> 1, wh = (t & 1) * 64;
        const float* g = W + wk * 128 + wh;
#pragma unroll
        for (int j = 0; j < 64; j += 4) {
            float4 v = *(const float4*)(g + j);
            Ws[wh + j + 0][wk] = tob(v.x);
            Ws[wh + j + 1][wk] = tob(v.y);
            Ws[wh + j + 2][wk] = tob(v.z);
            Ws[wh + j + 3][wk] = tob(v.w);
        }
    }
    __syncthreads();

    const int wave = t >> 6, lane = t & 63;
    const int lr = lane & 15, kb = lane >> 4;
    const int wm = wave * 16;

    f32x4 acc[8];
#pragma unroll
    for (int ct = 0; ct < 8; ++ct) acc[ct] = (f32x4){0.f, 0.f, 0.f, 0.f};

#pragma unroll
    for (int step = 0; step < 4; ++step) {
        const int ka = step * 32 + kb * 8;
        bf16x8 af = *(const bf16x8*)&Xs[wm + lr][ka];
#pragma unroll
        for (int ct = 0; ct < 8; ++ct) {
            bf16x8 bfr = *(const bf16x8*)&Ws[ct * 16 + lr][ka];
            acc[ct] = __builtin_amdgcn_mfma_f32_16x16x32_bf16(af, bfr, acc[ct], 0, 0, 0);
        }
    }

    // xt: row = t>>2, quarter q = t&3 (lanes 4r..4r+3 contiguous in wave)
    {
        const int row = t >> 2, q = t & 3;
        float p = 0.f;
#pragma unroll
        for (int kk = 0; kk < 32; ++kk)
            p += (float)Xs[row][q * 32 + kk] * theta[q * 32 + kk];
        p += __shfl_down(p, 2);
        p += __shfl_down(p, 1);
        if (q == 0) xt[r0 + row] = p;
    }

    // epilogue: col = ct*16+lr, local row = kb*4+i
#pragma unroll
    for (int ct = 0; ct < 8; ++ct) {
        const int col = ct * 16 + lr;
        const float bd = bias[col];
#pragma unroll
        for (int i = 0; i < 4; ++i)
            xw[(r0 + wm + kb * 4 + i) * 128 + col] = acc[ct][i] + bd;
    }
}

// ---------------------------------------------------------------------------
// Row bitmask + fused ELL row-list build (R13 proven).
__global__ __launch_bounds__(256) void bmask_lists_k(const float* __restrict__ inc,
                                                     u64* __restrict__ rowmask,
                                                     u16* __restrict__ idx,
                                                     int* __restrict__ cnts) {
    const int b = blockIdx.y;
    const int n = blockIdx.x * 4 + (threadIdx.x >> 6);
    const int l = threadIdx.x & 63;
    const float* p = inc + ((long)b << 24) + (long)n * 4096 + l * 64;
    u64 w = 0;
#pragma unroll
    for (int j = 0; j < 16; ++j) {
        const float4 v = *(const float4*)(p + j * 4);
        w |= (u64)(v.x != 0.f ? 1u : 0u) << (4 * j);
        w |= (u64)(v.y != 0.f ? 1u : 0u) << (4 * j + 1);
        w |= (u64)(v.z != 0.f ? 1u : 0u) << (4 * j + 2);
        w |= (u64)(v.w != 0.f ? 1u : 0u) << (4 * j + 3);
    }
    const long rowid = (long)b * 4096 + n;
    rowmask[rowid * 64 + l] = w;

    const int pc = __popcll(w);
    int pre = pc;
#pragma unroll
    for (int o = 1; o < 64; o <<= 1) {
        int t = __shfl_up(pre, o);
        if (l >= o) pre += t;
    }
    if (l == 63) cnts[rowid] = pre;
    u16* op = idx + rowid * CAP;
    int k = pre - pc;
    u64 m = w;
    while (m) {
        const int bit = __builtin_ctzll(m);
        m &= m - 1;
        if (k < CAP) op[k] = (u16)(l * 64 + bit);
        ++k;
    }
}

// 64x64 bit-tile transpose (incident masks) — R13 proven, 16384 blocks.
__global__ void btrans_k(const u64* __restrict__ rowmask, u64* __restrict__ colmask) {
    const int tn = blockIdx.x, te = blockIdx.y, b = blockIdx.z;
    const int l = threadIdx.x;
    __shared__ u64 w[64];
    w[l] = rowmask[((long)b * 4096 + tn * 64 + l) * 64 + te];
    __syncthreads();
    u64 o = 0;
#pragma unroll 8
    for (int j = 0; j < 64; ++j) o |= ((w[j] >> l) & 1ull) << j;
    colmask[((long)b * 4096 + te * 64 + l) * 64 + tn] = o;
}

// ---------------------------------------------------------------------------
// ELL list build from a mask (colmask path) — R13 proven.
__global__ __launch_bounds__(256) void lists_k(const u64* __restrict__ mask,
                                               u16* __restrict__ idx,
                                               int* __restrict__ cnts) {
    const int b = blockIdx.y;
    const int r = blockIdx.x * 4 + (threadIdx.x >> 6);
    const int l = threadIdx.x & 63;
    u64 m = mask[((long)b * 4096 + r) * 64 + l];
    const int pc = __popcll(m);
    int pre = pc;
#pragma unroll
    for (int o = 1; o < 64; o <<= 1) {
        int t = __shfl_up(pre, o);
        if (l >= o) pre += t;
    }
    if (l == 63) cnts[b * 4096 + r] = pre;
    u16* op = idx + ((long)b * 4096 + r) * CAP;
    int k = pre - pc;
    while (m) {
        const int bit = __builtin_ctzll(m);
        m &= m - 1;
        if (k < CAP) op[k] = (u16)(l * 64 + bit);
        ++k;
    }
}

// ---------------------------------------------------------------------------
// masked softmax over E per batch.
__global__ void softmax_k(const float* __restrict__ sc, const int* __restrict__ mask,
                          float* __restrict__ attn) {
    const int b = blockIdx.x, t = threadIdx.x;
    __shared__ float red[1024];
    const float* sb = sc + b * 4096;
    const int* mb = mask + b * 4096;

    float mx = -1e30f;
    for (int e = t; e < 4096; e += 1024)
        if (mb[e] != 0) mx = fmaxf(mx, sb[e]);
    red[t] = mx;
    __syncthreads();
    for (int st = 512; st > 0; st >>= 1) {
        if (t < st) red[t] = fmaxf(red[t], red[t + st]);
        __syncthreads();
    }
    mx = red[0];
    __syncthreads();

    float sum = 0.f;
    for (int e = t; e < 4096; e += 1024)
        if (mb[e] != 0) sum += expf(sb[e] - mx);
    red[t] = sum;
    __syncthreads();
    for (int st = 512; st > 0; st >>= 1) {
        if (t < st) red[t] += red[t + st];
        __syncthreads();
    }
    const float inv = 1.f / red[0];
    for (int e = t; e < 4096; e += 1024)
        attn[b * 4096 + e] = (mb[e] != 0) ? expf(sb[e] - mx) * inv : 0.f;
}

// ---------------------------------------------------------------------------
// hxw_s = attn (per edge row) * hxw.
__global__ __launch_bounds__(256) void scale_k(const float* __restrict__ hxw,
                                               const float* __restrict__ att,
                                               float* __restrict__ outp) {
    const long i4 = (long)blockIdx.x * 256 + threadIdx.x;
    float4 v = ((const float4*)hxw)[i4];
    const float s = att[i4 >> 5];
    v.x *= s; v.y *= s; v.z *= s; v.w *= s;
    ((float4*)outp)[i4] = v;
}

// ---------------------------------------------------------------------------
// Sum of split-K partials, optional +eps*H:  O = sum_s P_s [+ eps*H].
template <int KSP, bool EPS>
__global__ __launch_bounds__(256) void pairsum_k(const float* __restrict__ P,
                                                 const float* __restrict__ H,
                                                 const float* __restrict__ epsp,
                                                 float* __restrict__ O) {
    const long i4 = (long)blockIdx.x * 256 + threadIdx.x;
    float4 a = ((const float4*)P)[i4];
#pragma unroll
    for (int s = 1; s < KSP; ++s) {
        float4 c = ((const float4*)P)[i4 + (long)s * 524288];
        a.x += c.x; a.y += c.y; a.z += c.z; a.w += c.w;
    }
    if (EPS) {
        const float e = epsp[0];
        float4 h = ((const float4*)H)[i4];
        a.x += e * h.x; a.y += e * h.y; a.z += e * h.z; a.w += e * h.w;
    }
    ((float4*)O)[i4] = a;
}

// ---------------------------------------------------------------------------
// Plain ELL gather, 8-edge rounds with index double-buffer prefetch (R13).
template <bool HXT, bool EPI>
__global__ __launch_bounds__(256) void gatherE_k(
    const u16* __restrict__ idx, const int* __restrict__ cnts,
    const u64* __restrict__ mask, const float* __restrict__ src,
    const float* __restrict__ xt,
    const float* __restrict__ bng, const float* __restrict__ bnb,
    const float* __restrict__ bnm, const float* __restrict__ bnv,
    float* __restrict__ out, float* __restrict__ hxt) {
    const int bid = blockIdx.x;
    const int slot = bid & 7;
    const int b = slot >> 1;
    const int chunk = (bid >> 3) * 2 + (slot & 1);
    const int r = chunk * 4 + (threadIdx.x >> 6);
    const int l = threadIdx.x & 63;
    const long rowid = (long)b * 4096 + r;
    const int cnt = cnts[rowid];
    const u16* ip = idx + rowid * CAP;
    const float* S = src + (long)b * 524288;
    const float* xb = xt + (long)b * 4096;
    const int c0 = 2 * l;

    float ax0 = 0.f, ax1 = 0.f, ax2 = 0.f, ax3 = 0.f;
    float ax4 = 0.f, ax5 = 0.f, ax6 = 0.f, ax7 = 0.f;
    float ay0 = 0.f, ay1 = 0.f, ay2 = 0.f, ay3 = 0.f;
    float ay4 = 0.f, ay5 = 0.f, ay6 = 0.f, ay7 = 0.f;
    float hacc = 0.f;

    const int n = cnt < CAP ? cnt : CAP;
    int i = 0;
    if (n >= 8) {
        u16x8 ia = *(const u16x8*)ip;
        for (; i + 8 <= n; i += 8) {
            const int e0 = ia[0], e1 = ia[1], e2 = ia[2], e3 = ia[3];
            const int e4 = ia[4], e5 = ia[5], e6 = ia[6], e7 = ia[7];
            const float2 v0 = *(const float2*)(S + (long)e0 * 128 + c0);
            const float2 v1 = *(const float2*)(S + (long)e1 * 128 + c0);
            const float2 v2 = *(const float2*)(S + (long)e2 * 128 + c0);
            const float2 v3 = *(const float2*)(S + (long)e3 * 128 + c0);
            const float2 v4 = *(const float2*)(S + (long)e4 * 128 + c0);
            const float2 v5 = *(const float2*)(S + (long)e5 * 128 + c0);
            const float2 v6 = *(const float2*)(S + (long)e6 * 128 + c0);
            const float2 v7 = *(const float2*)(S + (long)e7 * 128 + c0);
            const bool more = (i + 16 <= n);
            u16x8 ib;
            if (more) ib = *(const u16x8*)(ip + i + 8);
            if (HXT)
                hacc += ((xb[e0] + xb[e1]) + (xb[e2] + xb[e3])) +
                        ((xb[e4] + xb[e5]) + (xb[e6] + xb[e7]));
            ax0 += v0.x; ay0 += v0.y; ax1 += v1.x; ay1 += v1.y;
            ax2 += v2.x; ay2 += v2.y; ax3 += v3.x; ay3 += v3.y;
            ax4 += v4.x; ay4 += v4.y; ax5 += v5.x; ay5 += v5.y;
            ax6 += v6.x; ay6 += v6.y; ax7 += v7.x; ay7 += v7.y;
            if (more) ia = ib;
        }
    }
    for (; i < n; ++i) {
        const int e = ip[i];
        const float2 v = *(const float2*)(S + (long)e * 128 + c0);
        if (HXT) hacc += xb[e];
        ax0 += v.x; ay0 += v.y;
    }

    if (cnt > CAP) {  // astronomically rare; exact fallback
        const u64 wrd = mask[rowid * 64 + l];
        int seen = 0;
        for (int wi = 0; wi < 64; ++wi) {
            u64 m = __shfl(wrd, wi);
            const int pc = __popcll(m);
            if (seen + pc > CAP) {
                int tk = CAP - seen;
                if (tk < 0) tk = 0;
                for (int t = 0; t < tk; ++t) m &= m - 1;
                while (m) {
                    const int bit = __builtin_ctzll(m);
                    m &= m - 1;
                    const int e = (wi << 6) + bit;
                    const float2 v = *(const float2*)(S + (long)e * 128 + c0);
                    if (HXT) hacc += xb[e];
                    ax0 += v.x; ay0 += v.y;
                }
            }
            seen += pc;
        }
    }

    float ax = ((ax0 + ax1) + (ax2 + ax3)) + ((ax4 + ax5) + (ax6 + ax7));
    float ay = ((ay0 + ay1) + (ay2 + ay3)) + ((ay4 + ay5) + (ay6 + ay7));
    if (EPI) {
        float t0 = (ax >= 0.f) ? ax : 0.01f * ax;
        float t1 = (ay >= 0.f) ? ay : 0.01f * ay;
        ax = (t0 - bnm[c0]) * rsqrtf(bnv[c0] + 1e-5f) * bng[c0] + bnb[c0];
        ay = (t1 - bnm[c0 + 1]) * rsqrtf(bnv[c0 + 1] + 1e-5f) * bng[c0 + 1] + bnb[c0 + 1];
    }
    *(float2*)&out[(long)b * 524288 + (long)r * 128 + c0] = (float2){ax, ay};
    if (HXT && l == 0) hxt[rowid] = hacc;
}

// ---------------------------------------------------------------------------
// Dense bf16-MFMA GEMM (R12/R13, frozen): 128x128 tile, 1024 thr = 16 waves,
// BK=64, LDS dbuf, 2 named reg sets, 1 barrier/phase, XCD-affinity 1D grid.
template <int KS>
__global__ __launch_bounds__(1024, 4) void gemm_dense(
    const float* __restrict__ A, const float* __restrict__ Bsrc,
    float* __restrict__ P) {
    __shared__ __align__(16) bf16 As[2][128][LDK];
    __shared__ __align__(16) bf16 Bs[2][128][LDK];

    const int tid = threadIdx.x;
    const int bid = blockIdx.x;
    const int slot = bid & 7;
    const int b = slot >> 1;
    const int sub = (bid >> 3) * 2 + (slot & 1);
    const int ksi = sub % KS;
    const int m0 = (sub / KS) * 128;
    constexpr int KCH = 4096 / KS;
    const int kbeg = ksi * KCH, kend = kbeg + KCH;
    const long Aoff = (long)b << 24;
    const long Boff = (long)b * 524288;

    const int wave = tid >> 6, lane = tid & 63;
    const int lr = lane & 15, kb = lane >> 4;
    const int wm = (wave >> 2) * 32, wn = (wave & 3) * 32;

    const int ar = tid >> 3, ak = (tid & 7) * 8;
    const int bd4 = (tid & 31) * 4, bk2 = (tid >> 5) * 2;

    const float* Abase = A + Aoff + (long)(m0 + ar) * 4096 + ak;
    const float* Bbase = Bsrc + Boff + (long)bk2 * 128 + bd4;

    f32x4 acc[2][2];
#pragma unroll
    for (int mf = 0; mf < 2; ++mf)
#pragma unroll
        for (int nf = 0; nf < 2; ++nf) acc[mf][nf] = (f32x4){0.f, 0.f, 0.f, 0.f};

    float4 pa0A, pa1A, pb0A, pb1A;
    float4 pa0B, pa1B, pb0B, pb1B;

#define GLOAD(S, kk)                                                        \
    {                                                                       \
        const float* ga = Abase + (kk);                                     \
        pa0##S = *(const float4*)ga;                                        \
        pa1##S = *(const float4*)(ga + 4);                                  \
        const float* gb = Bbase + (long)(kk) * 128;                         \
        pb0##S = *(const float4*)gb;                                        \
        pb1##S = *(const float4*)(gb + 128);                                \
    }

#define STAGE(S, bu)                                                        \
    {                                                                       \
        bf16x8 p;                                                           \
        p[0] = tob(pa0##S.x); p[1] = tob(pa0##S.y); p[2] = tob(pa0##S.z); p[3] = tob(pa0##S.w); \
        p[4] = tob(pa1##S.x); p[5] = tob(pa1##S.y); p[6] = tob(pa1##S.z); p[7] = tob(pa1##S.w); \
        *(bf16x8*)&As[bu][ar][SWZ(ar, ak)] = p;                             \
        float va[4] = {pb0##S.x, pb0##S.y, pb0##S.z, pb0##S.w};             \
        float vb[4] = {pb1##S.x, pb1##S.y, pb1##S.z, pb1##S.w};             \
        _Pragma("unroll")                                                   \
        for (int j = 0; j < 4; ++j) {                                       \
            BPack q; q.h[0] = tob(va[j]); q.h[1] = tob(vb[j]);              \
            *(unsigned int*)&Bs[bu][bd4 + j][SWZ(bd4 + j, bk2)] = q.u;      \
        }                                                                   \
    }

#define MFMA_STEP(bu)                                                       \
    {                                                                       \
        _Pragma("unroll")                                                   \
        for (int ks = 0; ks < 2; ++ks) {                                    \
            const int ka = ks * 32 + kb * 8;                                \
            bf16x8 af[2], bfr[2];                                           \
            _Pragma("unroll")                                               \
            for (int mf = 0; mf < 2; ++mf) {                                \
                const int rA = wm + mf * 16 + lr;                           \
                af[mf] = *(const bf16x8*)&As[bu][rA][SWZ(rA, ka)];          \
            }                                                               \
            _Pragma("unroll")                                               \
            for (int nf = 0; nf < 2; ++nf) {                                \
                const int rB = wn + nf * 16 + lr;                           \
                bfr[nf] = *(const bf16x8*)&Bs[bu][rB][SWZ(rB, ka)];         \
            }                                                               \
            _Pragma("unroll")                                               \
            for (int mf = 0; mf < 2; ++mf)                                  \
                _Pragma("unroll")                                           \
                for (int nf = 0; nf < 2; ++nf)                              \
                    acc[mf][nf] = __builtin_amdgcn_mfma_f32_16x16x32_bf16(  \
                        af[mf], bfr[nf], acc[mf][nf], 0, 0, 0);             \
        }                                                                   \
    }

    GLOAD(A, kbeg);
    GLOAD(B, kbeg + 64);
    STAGE(A, 0);
    __syncthreads();

    for (int kk = kbeg; kk < kend; kk += 128) {
        MFMA_STEP(0);
        STAGE(B, 1);
        if (kk + 128 < kend) GLOAD(A, kk + 128);
        __syncthreads();
        MFMA_STEP(1);
        if (kk + 128 < kend) {
            STAGE(A, 0);
            if (kk + 192 < kend) GLOAD(B, kk + 192);
            __syncthreads();
        }
    }
#undef GLOAD
#undef STAGE
#undef MFMA_STEP

    float* Cp = P + (long)(ksi * 4 + b) * 524288;
#pragma unroll
    for (int mf = 0; mf < 2; ++mf) {
        const int rb = m0 + wm + mf * 16 + kb * 4;
#pragma unroll
        for (int nf = 0; nf < 2; ++nf) {
            const int col = wn + nf * 16 + lr;
#pragma unroll
            for (int i = 0; i < 4; ++i)
                Cp[(long)(rb + i) * 128 + col] = acc[mf][nf][i];
        }
    }
}

// ---------------------------------------------------------------------------
template <int KS>
static void run_all(const float* incident, const float* degree_v, const float* degree_e,
                    const float* x, const int* e_masks, const float* mlp_W,
                    const float* mlp_b, const float* theta, const float* epsp,
                    const float* bng, const float* bnb, const float* bnm,
                    const float* bnv, float* out, float* ws, hipStream_t stream) {
    float* xw    = ws;                        // 2M floats
    float* hxw   = ws + 2097152;              // 2M
    float* hxw_s = ws + 4194304;              // 2M
    float* t1    = ws + 6291456;              // 2M
    float* Pd    = ws + 8388608;              // KS*2M
    float* Psum  = Pd + (long)KS * 2097152;   // 2M
    float* tail  = Psum + 2097152;
    u64* rowmask = (u64*)tail;                       // 1M u64
    u64* colmask = rowmask + 1048576;                // 1M u64
    u16* rowidx = (u16*)(colmask + 1048576);         // 16384*CAP u16
    u16* colidx = rowidx + 16384 * CAP;
    int* rowcnt = (int*)(colidx + 16384 * CAP);      // 16K int
    int* colcnt = rowcnt + 16384;
    float* xt  = (float*)(colcnt + 16384);
    float* hxt = xt + 16384;
    float* att = hxt + 16384;

    mlp_k<<<256, 256, 0, stream>>>(x, mlp_W, mlp_b, theta, xw, xt);
    bmask_lists_k<<<dim3(1024, 4), 256, 0, stream>>>(incident, rowmask, rowidx, rowcnt);
    btrans_k<<<dim3(64, 64, 4), 64, 0, stream>>>(rowmask, colmask);
    lists_k<<<dim3(1024, 4), 256, 0, stream>>>(colmask, colidx, colcnt);

    // G1: hxw = Ht @ xw  (+ hxt = Ht @ xt)
    gatherE_k<true, false><<<4096, 256, 0, stream>>>(
        colidx, colcnt, colmask, xw, xt, nullptr, nullptr, nullptr, nullptr,
        hxw, hxt);
    softmax_k<<<4, 1024, 0, stream>>>(hxt, e_masks, att);
    scale_k<<<2048, 256, 0, stream>>>(hxw, att, hxw_s);
    // G2: t1 = incident @ hxw_s
    gatherE_k<false, false><<<4096, 256, 0, stream>>>(
        rowidx, rowcnt, rowmask, hxw_s, xt, nullptr, nullptr, nullptr, nullptr,
        t1, nullptr);
    // G3: Pd = degree_v @ t1
    gemm_dense<KS><<<32 * KS * 4, 1024, 0, stream>>>(degree_v, t1, Pd);
    pairsum_k<KS, false><<<2048, 256, 0, stream>>>(Pd, nullptr, nullptr, Psum);
    // G4: t1 = Ht @ Psum
    gatherE_k<false, false><<<4096, 256, 0, stream>>>(
        colidx, colcnt, colmask, Psum, xt, nullptr, nullptr, nullptr, nullptr,
        t1, nullptr);
    // G5: Pd = degree_e @ t1
    gemm_dense<KS><<<32 * KS * 4, 1024, 0, stream>>>(degree_e, t1, Pd);
    pairsum_k<KS, true><<<2048, 256, 0, stream>>>(Pd, hxw, epsp, Psum);
    // G6: out = BN(leaky(incident @ Psum))
    gatherE_k<false, true><<<4096, 256, 0, stream>>>(
        rowidx, rowcnt, rowmask, Psum, xt, bng, bnb, bnm, bnv, out, nullptr);
}

extern "C" void kernel_launch(void* const* d_in, const int* in_sizes, int n_in,
                              void* d_out, int out_size, void* d_ws, size_t ws_size,
                              hipStream_t stream) {
    const float* incident = (const float*)d_in[0];
    const float* degree_v = (const float*)d_in[1];
    const float* degree_e = (const float*)d_in[2];
    const float* x        = (const float*)d_in[3];
    const int*   e_masks  = (const int*)d_in[4];
    const float* mlp_W    = (const float*)d_in[5];
    const float* mlp_b    = (const float*)d_in[6];
    const float* theta    = (const float*)d_in[7];
    const float* epsp     = (const float*)d_in[8];
    const float* bng      = (const float*)d_in[9];
    const float* bnb      = (const float*)d_in[10];
    const float* bnm      = (const float*)d_in[11];
    const float* bnv      = (const float*)d_in[12];
    float* out = (float*)d_out;
    float* ws = (float*)d_ws;

    if (ws_size >= 110000000ull)
        run_all<2>(incident, degree_v, degree_e, x, e_masks, mlp_W, mlp_b, theta,
                   epsp, bng, bnb, bnm, bnv, out, ws, stream);
    else
        run_all<1>(incident, degree_v, degree_e, x, e_masks, mlp_W, mlp_b, theta,
                   epsp, bng, bnb, bnm, bnv, out, ws, stream);
}

// Round 18
// 362.766 us; speedup vs baseline: 1.2223x; 1.0625x over previous
//
#include <hip/hip_runtime.h>

// HGNN layer, B=4, N=E=4096, D=128, fp32 in/out.
// Round 18: R17 retry (macro-paste fix: ev##j names). Gather v3 — float4
// lanes with 2-edge interleave (16 edges/round, 128B/lane in flight,
// predicated final round, shfl_xor(32) half-combine). Rest identical to R16.

typedef __bf16 bf16;
typedef bf16 bf16x8 __attribute__((ext_vector_type(8)));
typedef float f32x4 __attribute__((ext_vector_type(4)));
typedef unsigned long long u64;
typedef unsigned short u16;
typedef u16 u16x8 __attribute__((ext_vector_type(8)));

#define LDK 72   // LDS row stride for 64-k tiles (gemm)
#define LDM 136  // LDS row stride for 128-k tiles (mlp)
#define SWZ(r, c) ((c) ^ ((((r) >> 3) & 7) << 3))
#define CAP 192

union BPack { bf16 h[2]; unsigned int u; };
static __device__ __forceinline__ bf16 tob(float f) { return (bf16)f; }

// ---------------------------------------------------------------------------
// K1 (MFMA): xw = x @ W + b, xt = x @ theta. 64 rows/block, 256 thr = 4 waves.
__global__ __launch_bounds__(256) void mlp_k(const float* __restrict__ x,
                                             const float* __restrict__ W,
                                             const float* __restrict__ bias,
                                             const float* __restrict__ theta,
                                             float* __restrict__ xw,
                                             float* __restrict__ xt) {
    __shared__ __align__(16) bf16 Xs[64][LDM];
    __shared__ __align__(16) bf16 Ws[128][LDM];  // Ws[d][k] = W[k][d]
    const int t = threadIdx.x;
    const long r0 = (long)blockIdx.x * 64;

    {
        const int row = t >> 2, c = (t & 3) * 32;
        const float* g = x + (r0 + row) * 128 + c;
#pragma unroll
        for (int j8 = 0; j8 < 4; ++j8) {
            float4 v0 = *(const float4*)(g + j8 * 8);
            float4 v1 = *(const float4*)(g + j8 * 8 + 4);
            bf16x8 p;
            p[0] = tob(v0.x); p[1] = tob(v0.y); p[2] = tob(v0.z); p[3] = tob(v0.w);
            p[4] = tob(v1.x); p[5] = tob(v1.y); p[6] = tob(v1.z); p[7] = tob(v1.w);
            *(bf16x8*)&Xs[row][c + j8 * 8] = p;
        }
    }
    {
        const int wk = t >> 1, wh = (t & 1) * 64;
        const float* g = W + wk * 128 + wh;
#pragma unroll
        for (int j = 0; j < 64; j += 4) {
            float4 v = *(const float4*)(g + j);
            Ws[wh + j + 0][wk] = tob(v.x);
            Ws[wh + j + 1][wk] = tob(v.y);
            Ws[wh + j + 2][wk] = tob(v.z);
            Ws[wh + j + 3][wk] = tob(v.w);
        }
    }
    __syncthreads();

    const int wave = t >> 6, lane = t & 63;
    const int lr = lane & 15, kb = lane >> 4;
    const int wm = wave * 16;

    f32x4 acc[8];
#pragma unroll
    for (int ct = 0; ct < 8; ++ct) acc[ct] = (f32x4){0.f, 0.f, 0.f, 0.f};

#pragma unroll
    for (int step = 0; step < 4; ++step) {
        const int ka = step * 32 + kb * 8;
        bf16x8 af = *(const bf16x8*)&Xs[wm + lr][ka];
#pragma unroll
        for (int ct = 0; ct < 8; ++ct) {
            bf16x8 bfr = *(const bf16x8*)&Ws[ct * 16 + lr][ka];
            acc[ct] = __builtin_amdgcn_mfma_f32_16x16x32_bf16(af, bfr, acc[ct], 0, 0, 0);
        }
    }

    {
        const int row = t >> 2, q = t & 3;
        float p = 0.f;
#pragma unroll
        for (int kk = 0; kk < 32; ++kk)
            p += (float)Xs[row][q * 32 + kk] * theta[q * 32 + kk];
        p += __shfl_down(p, 2);
        p += __shfl_down(p, 1);
        if (q == 0) xt[r0 + row] = p;
    }

#pragma unroll
    for (int ct = 0; ct < 8; ++ct) {
        const int col = ct * 16 + lr;
        const float bd = bias[col];
#pragma unroll
        for (int i = 0; i < 4; ++i)
            xw[(r0 + wm + kb * 4 + i) * 128 + col] = acc[ct][i] + bd;
    }
}

// ---------------------------------------------------------------------------
// Row bitmask + fused ELL row-list build (R13 proven).
__global__ __launch_bounds__(256) void bmask_lists_k(const float* __restrict__ inc,
                                                     u64* __restrict__ rowmask,
                                                     u16* __restrict__ idx,
                                                     int* __restrict__ cnts) {
    const int b = blockIdx.y;
    const int n = blockIdx.x * 4 + (threadIdx.x >> 6);
    const int l = threadIdx.x & 63;
    const float* p = inc + ((long)b << 24) + (long)n * 4096 + l * 64;
    u64 w = 0;
#pragma unroll
    for (int j = 0; j < 16; ++j) {
        const float4 v = *(const float4*)(p + j * 4);
        w |= (u64)(v.x != 0.f ? 1u : 0u) << (4 * j);
        w |= (u64)(v.y != 0.f ? 1u : 0u) << (4 * j + 1);
        w |= (u64)(v.z != 0.f ? 1u : 0u) << (4 * j + 2);
        w |= (u64)(v.w != 0.f ? 1u : 0u) << (4 * j + 3);
    }
    const long rowid = (long)b * 4096 + n;
    rowmask[rowid * 64 + l] = w;

    const int pc = __popcll(w);
    int pre = pc;
#pragma unroll
    for (int o = 1; o < 64; o <<= 1) {
        int t = __shfl_up(pre, o);
        if (l >= o) pre += t;
    }
    if (l == 63) cnts[rowid] = pre;
    u16* op = idx + rowid * CAP;
    int k = pre - pc;
    u64 m = w;
    while (m) {
        const int bit = __builtin_ctzll(m);
        m &= m - 1;
        if (k < CAP) op[k] = (u16)(l * 64 + bit);
        ++k;
    }
}

// 64x64 bit-tile transpose (incident masks) — R13 proven.
__global__ void btrans_k(const u64* __restrict__ rowmask, u64* __restrict__ colmask) {
    const int tn = blockIdx.x, te = blockIdx.y, b = blockIdx.z;
    const int l = threadIdx.x;
    __shared__ u64 w[64];
    w[l] = rowmask[((long)b * 4096 + tn * 64 + l) * 64 + te];
    __syncthreads();
    u64 o = 0;
#pragma unroll 8
    for (int j = 0; j < 64; ++j) o |= ((w[j] >> l) & 1ull) << j;
    colmask[((long)b * 4096 + te * 64 + l) * 64 + tn] = o;
}

// ---------------------------------------------------------------------------
// ELL list build from a mask (colmask path) — R13 proven.
__global__ __launch_bounds__(256) void lists_k(const u64* __restrict__ mask,
                                               u16* __restrict__ idx,
                                               int* __restrict__ cnts) {
    const int b = blockIdx.y;
    const int r = blockIdx.x * 4 + (threadIdx.x >> 6);
    const int l = threadIdx.x & 63;
    u64 m = mask[((long)b * 4096 + r) * 64 + l];
    const int pc = __popcll(m);
    int pre = pc;
#pragma unroll
    for (int o = 1; o < 64; o <<= 1) {
        int t = __shfl_up(pre, o);
        if (l >= o) pre += t;
    }
    if (l == 63) cnts[b * 4096 + r] = pre;
    u16* op = idx + ((long)b * 4096 + r) * CAP;
    int k = pre - pc;
    while (m) {
        const int bit = __builtin_ctzll(m);
        m &= m - 1;
        if (k < CAP) op[k] = (u16)(l * 64 + bit);
        ++k;
    }
}

// ---------------------------------------------------------------------------
// masked softmax over E per batch.
__global__ void softmax_k(const float* __restrict__ sc, const int* __restrict__ mask,
                          float* __restrict__ attn) {
    const int b = blockIdx.x, t = threadIdx.x;
    __shared__ float red[1024];
    const float* sb = sc + b * 4096;
    const int* mb = mask + b * 4096;

    float mx = -1e30f;
    for (int e = t; e < 4096; e += 1024)
        if (mb[e] != 0) mx = fmaxf(mx, sb[e]);
    red[t] = mx;
    __syncthreads();
    for (int st = 512; st > 0; st >>= 1) {
        if (t < st) red[t] = fmaxf(red[t], red[t + st]);
        __syncthreads();
    }
    mx = red[0];
    __syncthreads();

    float sum = 0.f;
    for (int e = t; e < 4096; e += 1024)
        if (mb[e] != 0) sum += expf(sb[e] - mx);
    red[t] = sum;
    __syncthreads();
    for (int st = 512; st > 0; st >>= 1) {
        if (t < st) red[t] += red[t + st];
        __syncthreads();
    }
    const float inv = 1.f / red[0];
    for (int e = t; e < 4096; e += 1024)
        attn[b * 4096 + e] = (mb[e] != 0) ? expf(sb[e] - mx) * inv : 0.f;
}

// ---------------------------------------------------------------------------
// hxw_s = attn (per edge row) * hxw.
__global__ __launch_bounds__(256) void scale_k(const float* __restrict__ hxw,
                                               const float* __restrict__ att,
                                               float* __restrict__ outp) {
    const long i4 = (long)blockIdx.x * 256 + threadIdx.x;
    float4 v = ((const float4*)hxw)[i4];
    const float s = att[i4 >> 5];
    v.x *= s; v.y *= s; v.z *= s; v.w *= s;
    ((float4*)outp)[i4] = v;
}

// ---------------------------------------------------------------------------
// Sum of split-K partials, optional +eps*H:  O = sum_s P_s [+ eps*H].
template <int KSP, bool EPS>
__global__ __launch_bounds__(256) void pairsum_k(const float* __restrict__ P,
                                                 const float* __restrict__ H,
                                                 const float* __restrict__ epsp,
                                                 float* __restrict__ O) {
    const long i4 = (long)blockIdx.x * 256 + threadIdx.x;
    float4 a = ((const float4*)P)[i4];
#pragma unroll
    for (int s = 1; s < KSP; ++s) {
        float4 c = ((const float4*)P)[i4 + (long)s * 524288];
        a.x += c.x; a.y += c.y; a.z += c.z; a.w += c.w;
    }
    if (EPS) {
        const float e = epsp[0];
        float4 h = ((const float4*)H)[i4];
        a.x += e * h.x; a.y += e * h.y; a.z += e * h.z; a.w += e * h.w;
    }
    ((float4*)O)[i4] = a;
}

// ---------------------------------------------------------------------------
// ELL gather v3: lane l covers cols 4*(l&31) for edges of parity l>>5.
// 16 edges/round via 8 float4 loads/lane (128B in flight), predicated final
// round (index clamp), halves combined with shfl_xor(32). XCD-affinity grid.
template <bool HXT, bool EPI>
__global__ __launch_bounds__(256) void gatherE_k(
    const u16* __restrict__ idx, const int* __restrict__ cnts,
    const u64* __restrict__ mask, const float* __restrict__ src,
    const float* __restrict__ xt,
    const float* __restrict__ bng, const float* __restrict__ bnb,
    const float* __restrict__ bnm, const float* __restrict__ bnv,
    float* __restrict__ out, float* __restrict__ hxt) {
    const int bid = blockIdx.x;
    const int slot = bid & 7;
    const int b = slot >> 1;
    const int chunk = (bid >> 3) * 2 + (slot & 1);
    const int r = chunk * 4 + (threadIdx.x >> 6);
    const int l = threadIdx.x & 63;
    const int lh = l >> 5;           // edge parity this lane handles
    const int c0 = 4 * (l & 31);     // 4-column slice
    const long rowid = (long)b * 4096 + r;
    const int cnt = cnts[rowid];
    const u16* ip = idx + rowid * CAP;
    const float* S = src + (long)b * 524288;
    const float* xb = xt + (long)b * 4096;

    f32x4 a0 = {0,0,0,0}, a1 = {0,0,0,0}, a2 = {0,0,0,0}, a3 = {0,0,0,0};
    f32x4 a4 = {0,0,0,0}, a5 = {0,0,0,0}, a6 = {0,0,0,0}, a7 = {0,0,0,0};
    float hacc = 0.f;

    const int n = cnt < CAP ? cnt : CAP;
    const int nr = (n + 15) >> 4;  // rounds of 16 edges

    u16x8 ia0, ia1, ib0, ib1;
    if (nr > 0) {
        ia0 = *(const u16x8*)ip;
        ia1 = *(const u16x8*)(ip + 8);
    }
    for (int rnd = 0; rnd < nr; ++rnd) {
        const int base = rnd << 4;
        // extract this lane's 8 edge indices (parity lh), clamp invalid to 0
        int ev0, ev1, ev2, ev3, ev4, ev5, ev6, ev7;
        bool kv0, kv1, kv2, kv3, kv4, kv5, kv6, kv7;
#define EXT(j, s8, i0, i1)                                              \
        {                                                               \
            const int raw = lh ? (int)s8[i1] : (int)s8[i0];             \
            const bool kk = (base + 2 * (j) + lh) < n;                  \
            ev##j = kk ? raw : 0;  kv##j = kk;                          \
        }
        EXT(0, ia0, 0, 1) EXT(1, ia0, 2, 3) EXT(2, ia0, 4, 5) EXT(3, ia0, 6, 7)
        EXT(4, ia1, 0, 1) EXT(5, ia1, 2, 3) EXT(6, ia1, 4, 5) EXT(7, ia1, 6, 7)
#undef EXT
        const float4 v0 = *(const float4*)(S + (long)ev0 * 128 + c0);
        const float4 v1 = *(const float4*)(S + (long)ev1 * 128 + c0);
        const float4 v2 = *(const float4*)(S + (long)ev2 * 128 + c0);
        const float4 v3 = *(const float4*)(S + (long)ev3 * 128 + c0);
        const float4 v4 = *(const float4*)(S + (long)ev4 * 128 + c0);
        const float4 v5 = *(const float4*)(S + (long)ev5 * 128 + c0);
        const float4 v6 = *(const float4*)(S + (long)ev6 * 128 + c0);
        const float4 v7 = *(const float4*)(S + (long)ev7 * 128 + c0);
        const bool more = (rnd + 1 < nr);
        if (more) {
            ib0 = *(const u16x8*)(ip + base + 16);
            ib1 = *(const u16x8*)(ip + base + 24);
        }
#define ACC(j, q)                                                       \
        if (kv##j) {                                                    \
            a##j[0] += q.x; a##j[1] += q.y; a##j[2] += q.z; a##j[3] += q.w; \
            if (HXT) hacc += xb[ev##j];                                 \
        }
        ACC(0, v0) ACC(1, v1) ACC(2, v2) ACC(3, v3)
        ACC(4, v4) ACC(5, v5) ACC(6, v6) ACC(7, v7)
#undef ACC
        if (more) { ia0 = ib0; ia1 = ib1; }
    }

    if (cnt > CAP) {  // astronomically rare; exact fallback (half-0 lanes only)
        const u64 wrd = mask[rowid * 64 + l];
        int seen = 0;
        for (int wi = 0; wi < 64; ++wi) {
            u64 m = __shfl(wrd, wi);
            const int pc = __popcll(m);
            if (seen + pc > CAP) {
                int tk = CAP - seen;
                if (tk < 0) tk = 0;
                for (int t = 0; t < tk; ++t) m &= m - 1;
                while (m) {
                    const int bit = __builtin_ctzll(m);
                    m &= m - 1;
                    const int e = (wi << 6) + bit;
                    if (lh == 0) {
                        const float4 v = *(const float4*)(S + (long)e * 128 + c0);
                        a0[0] += v.x; a0[1] += v.y; a0[2] += v.z; a0[3] += v.w;
                        if (HXT) hacc += xb[e];
                    }
                }
            }
            seen += pc;
        }
    }

    f32x4 s = ((a0 + a1) + (a2 + a3)) + ((a4 + a5) + (a6 + a7));
    float sx = s[0] + __shfl_xor(s[0], 32);
    float sy = s[1] + __shfl_xor(s[1], 32);
    float sz = s[2] + __shfl_xor(s[2], 32);
    float sw = s[3] + __shfl_xor(s[3], 32);
    if (HXT) {
        hacc += __shfl_xor(hacc, 32);
        if (l == 0) hxt[rowid] = hacc;
    }
    if (l < 32) {
        if (EPI) {
            const float4 bm = *(const float4*)&bnm[c0];
            const float4 bv = *(const float4*)&bnv[c0];
            const float4 bg = *(const float4*)&bng[c0];
            const float4 bb = *(const float4*)&bnb[c0];
            float t0 = (sx >= 0.f) ? sx : 0.01f * sx;
            float t1 = (sy >= 0.f) ? sy : 0.01f * sy;
            float t2 = (sz >= 0.f) ? sz : 0.01f * sz;
            float t3 = (sw >= 0.f) ? sw : 0.01f * sw;
            sx = (t0 - bm.x) * rsqrtf(bv.x + 1e-5f) * bg.x + bb.x;
            sy = (t1 - bm.y) * rsqrtf(bv.y + 1e-5f) * bg.y + bb.y;
            sz = (t2 - bm.z) * rsqrtf(bv.z + 1e-5f) * bg.z + bb.z;
            sw = (t3 - bm.w) * rsqrtf(bv.w + 1e-5f) * bg.w + bb.w;
        }
        *(float4*)&out[(long)b * 524288 + (long)r * 128 + c0] =
            (float4){sx, sy, sz, sw};
    }
}

// ---------------------------------------------------------------------------
// Dense bf16-MFMA GEMM (R12/R13, frozen): 128x128 tile, 1024 thr = 16 waves,
// BK=64, LDS dbuf, 2 named reg sets, 1 barrier/phase, XCD-affinity 1D grid.
template <int KS>
__global__ __launch_bounds__(1024, 4) void gemm_dense(
    const float* __restrict__ A, const float* __restrict__ Bsrc,
    float* __restrict__ P) {
    __shared__ __align__(16) bf16 As[2][128][LDK];
    __shared__ __align__(16) bf16 Bs[2][128][LDK];

    const int tid = threadIdx.x;
    const int bid = blockIdx.x;
    const int slot = bid & 7;
    const int b = slot >> 1;
    const int sub = (bid >> 3) * 2 + (slot & 1);
    const int ksi = sub % KS;
    const int m0 = (sub / KS) * 128;
    constexpr int KCH = 4096 / KS;
    const int kbeg = ksi * KCH, kend = kbeg + KCH;
    const long Aoff = (long)b << 24;
    const long Boff = (long)b * 524288;

    const int wave = tid >> 6, lane = tid & 63;
    const int lr = lane & 15, kb = lane >> 4;
    const int wm = (wave >> 2) * 32, wn = (wave & 3) * 32;

    const int ar = tid >> 3, ak = (tid & 7) * 8;
    const int bd4 = (tid & 31) * 4, bk2 = (tid >> 5) * 2;

    const float* Abase = A + Aoff + (long)(m0 + ar) * 4096 + ak;
    const float* Bbase = Bsrc + Boff + (long)bk2 * 128 + bd4;

    f32x4 acc[2][2];
#pragma unroll
    for (int mf = 0; mf < 2; ++mf)
#pragma unroll
        for (int nf = 0; nf < 2; ++nf) acc[mf][nf] = (f32x4){0.f, 0.f, 0.f, 0.f};

    float4 pa0A, pa1A, pb0A, pb1A;
    float4 pa0B, pa1B, pb0B, pb1B;

#define GLOAD(S, kk)                                                        \
    {                                                                       \
        const float* ga = Abase + (kk);                                     \
        pa0##S = *(const float4*)ga;                                        \
        pa1##S = *(const float4*)(ga + 4);                                  \
        const float* gb = Bbase + (long)(kk) * 128;                         \
        pb0##S = *(const float4*)gb;                                        \
        pb1##S = *(const float4*)(gb + 128);                                \
    }

#define STAGE(S, bu)                                                        \
    {                                                                       \
        bf16x8 p;                                                           \
        p[0] = tob(pa0##S.x); p[1] = tob(pa0##S.y); p[2] = tob(pa0##S.z); p[3] = tob(pa0##S.w); \
        p[4] = tob(pa1##S.x); p[5] = tob(pa1##S.y); p[6] = tob(pa1##S.z); p[7] = tob(pa1##S.w); \
        *(bf16x8*)&As[bu][ar][SWZ(ar, ak)] = p;                             \
        float va[4] = {pb0##S.x, pb0##S.y, pb0##S.z, pb0##S.w};             \
        float vb[4] = {pb1##S.x, pb1##S.y, pb1##S.z, pb1##S.w};             \
        _Pragma("unroll")                                                   \
        for (int j = 0; j < 4; ++j) {                                       \
            BPack q; q.h[0] = tob(va[j]); q.h[1] = tob(vb[j]);              \
            *(unsigned int*)&Bs[bu][bd4 + j][SWZ(bd4 + j, bk2)] = q.u;      \
        }                                                                   \
    }

#define MFMA_STEP(bu)                                                       \
    {                                                                       \
        _Pragma("unroll")                                                   \
        for (int ks = 0; ks < 2; ++ks) {                                    \
            const int ka = ks * 32 + kb * 8;                                \
            bf16x8 af[2], bfr[2];                                           \
            _Pragma("unroll")                                               \
            for (int mf = 0; mf < 2; ++mf) {                                \
                const int rA = wm + mf * 16 + lr;                           \
                af[mf] = *(const bf16x8*)&As[bu][rA][SWZ(rA, ka)];          \
            }                                                               \
            _Pragma("unroll")                                               \
            for (int nf = 0; nf < 2; ++nf) {                                \
                const int rB = wn + nf * 16 + lr;                           \
                bfr[nf] = *(const bf16x8*)&Bs[bu][rB][SWZ(rB, ka)];         \
            }                                                               \
            _Pragma("unroll")                                               \
            for (int mf = 0; mf < 2; ++mf)                                  \
                _Pragma("unroll")                                           \
                for (int nf = 0; nf < 2; ++nf)                              \
                    acc[mf][nf] = __builtin_amdgcn_mfma_f32_16x16x32_bf16(  \
                        af[mf], bfr[nf], acc[mf][nf], 0, 0, 0);             \
        }                                                                   \
    }

    GLOAD(A, kbeg);
    GLOAD(B, kbeg + 64);
    STAGE(A, 0);
    __syncthreads();

    for (int kk = kbeg; kk < kend; kk += 128) {
        MFMA_STEP(0);
        STAGE(B, 1);
        if (kk + 128 < kend) GLOAD(A, kk + 128);
        __syncthreads();
        MFMA_STEP(1);
        if (kk + 128 < kend) {
            STAGE(A, 0);
            if (kk + 192 < kend) GLOAD(B, kk + 192);
            __syncthreads();
        }
    }
#undef GLOAD
#undef STAGE
#undef MFMA_STEP

    float* Cp = P + (long)(ksi * 4 + b) * 524288;
#pragma unroll
    for (int mf = 0; mf < 2; ++mf) {
        const int rb = m0 + wm + mf * 16 + kb * 4;
#pragma unroll
        for (int nf = 0; nf < 2; ++nf) {
            const int col = wn + nf * 16 + lr;
#pragma unroll
            for (int i = 0; i < 4; ++i)
                Cp[(long)(rb + i) * 128 + col] = acc[mf][nf][i];
        }
    }
}

// ---------------------------------------------------------------------------
template <int KS>
static void run_all(const float* incident, const float* degree_v, const float* degree_e,
                    const float* x, const int* e_masks, const float* mlp_W,
                    const float* mlp_b, const float* theta, const float* epsp,
                    const float* bng, const float* bnb, const float* bnm,
                    const float* bnv, float* out, float* ws, hipStream_t stream) {
    float* xw    = ws;                        // 2M floats
    float* hxw   = ws + 2097152;              // 2M
    float* hxw_s = ws + 4194304;              // 2M
    float* t1    = ws + 6291456;              // 2M
    float* Pd    = ws + 8388608;              // KS*2M
    float* Psum  = Pd + (long)KS * 2097152;   // 2M
    float* tail  = Psum + 2097152;
    u64* rowmask = (u64*)tail;                       // 1M u64
    u64* colmask = rowmask + 1048576;                // 1M u64
    u16* rowidx = (u16*)(colmask + 1048576);         // 16384*CAP u16
    u16* colidx = rowidx + 16384 * CAP;
    int* rowcnt = (int*)(colidx + 16384 * CAP);      // 16K int
    int* colcnt = rowcnt + 16384;
    float* xt  = (float*)(colcnt + 16384);
    float* hxt = xt + 16384;
    float* att = hxt + 16384;

    mlp_k<<<256, 256, 0, stream>>>(x, mlp_W, mlp_b, theta, xw, xt);
    bmask_lists_k<<<dim3(1024, 4), 256, 0, stream>>>(incident, rowmask, rowidx, rowcnt);
    btrans_k<<<dim3(64, 64, 4), 64, 0, stream>>>(rowmask, colmask);
    lists_k<<<dim3(1024, 4), 256, 0, stream>>>(colmask, colidx, colcnt);

    // G1: hxw = Ht @ xw  (+ hxt = Ht @ xt)
    gatherE_k<true, false><<<4096, 256, 0, stream>>>(
        colidx, colcnt, colmask, xw, xt, nullptr, nullptr, nullptr, nullptr,
        hxw, hxt);
    softmax_k<<<4, 1024, 0, stream>>>(hxt, e_masks, att);
    scale_k<<<2048, 256, 0, stream>>>(hxw, att, hxw_s);
    // G2: t1 = incident @ hxw_s
    gatherE_k<false, false><<<4096, 256, 0, stream>>>(
        rowidx, rowcnt, rowmask, hxw_s, xt, nullptr, nullptr, nullptr, nullptr,
        t1, nullptr);
    // G3: Pd = degree_v @ t1
    gemm_dense<KS><<<32 * KS * 4, 1024, 0, stream>>>(degree_v, t1, Pd);
    pairsum_k<KS, false><<<2048, 256, 0, stream>>>(Pd, nullptr, nullptr, Psum);
    // G4: t1 = Ht @ Psum
    gatherE_k<false, false><<<4096, 256, 0, stream>>>(
        colidx, colcnt, colmask, Psum, xt, nullptr, nullptr, nullptr, nullptr,
        t1, nullptr);
    // G5: Pd = degree_e @ t1
    gemm_dense<KS><<<32 * KS * 4, 1024, 0, stream>>>(degree_e, t1, Pd);
    pairsum_k<KS, true><<<2048, 256, 0, stream>>>(Pd, hxw, epsp, Psum);
    // G6: out = BN(leaky(incident @ Psum))
    gatherE_k<false, true><<<4096, 256, 0, stream>>>(
        rowidx, rowcnt, rowmask, Psum, xt, bng, bnb, bnm, bnv, out, nullptr);
}

extern "C" void kernel_launch(void* const* d_in, const int* in_sizes, int n_in,
                              void* d_out, int out_size, void* d_ws, size_t ws_size,
                              hipStream_t stream) {
    const float* incident = (const float*)d_in[0];
    const float* degree_v = (const float*)d_in[1];
    const float* degree_e = (const float*)d_in[2];
    const float* x        = (const float*)d_in[3];
    const int*   e_masks  = (const int*)d_in[4];
    const float* mlp_W    = (const float*)d_in[5];
    const float* mlp_b    = (const float*)d_in[6];
    const float* theta    = (const float*)d_in[7];
    const float* epsp     = (const float*)d_in[8];
    const float* bng      = (const float*)d_in[9];
    const float* bnb      = (const float*)d_in[10];
    const float* bnm      = (const float*)d_in[11];
    const float* bnv      = (const float*)d_in[12];
    float* out = (float*)d_out;
    float* ws = (float*)d_ws;

    if (ws_size >= 110000000ull)
        run_all<2>(incident, degree_v, degree_e, x, e_masks, mlp_W, mlp_b, theta,
                   epsp, bng, bnb, bnm, bnv, out, ws, stream);
    else
        run_all<1>(incident, degree_v, degree_e, x, e_masks, mlp_W, mlp_b, theta,
                   epsp, bng, bnb, bnm, bnv, out, ws, stream);
}